// Round 5
// baseline (211.148 us; speedup 1.0000x reference)
//
#include <hip/hip_runtime.h>
#include <stdint.h>

// Shapes (fixed by the reference)
#define B_ 8
#define N_ 1024
#define D_ 512
#define H_ 8
#define DH_ 64

// Round 5: k_attn rewrite.
//  - R4's 67us regression was a scratch spill of the uint4 hv[8] staging array
//    (VGPR_Count 52, WRITE_SIZE 131MB ~= 256thr*128B*1024blk*4chunks). Fixed:
//    __launch_bounds__(256,3) + staging in two 4-uint4 batches.
//  - exp moved out of the per-edge loop: exp(lrelu(fs+fd)) ==
//    max(e^fs*e^fd, e^{0.2fs}*e^{0.2fd})  (e^s >= e^{0.2s} iff s>=0).
//    Per-j tables (Ed,Ed2) in LDS; per-i (Es,Es2) in regs.
//  - softmax denominator from MFMA: 16 all-ones bf16 rows appended to Hs give
//    l_i in acc[4]; psum/shuffles/ilrow deleted.

using bf16x8 = __attribute__((ext_vector_type(8))) __bf16;
using f32x4  = __attribute__((ext_vector_type(4))) float;

__device__ __forceinline__ float bf2f(uint32_t u) {
  union { uint32_t u; float f; } c; c.u = u << 16; return c.f;
}
__device__ __forceinline__ uint16_t f2bf(float f) {  // RNE
  union { float f; uint32_t u; } c; c.f = f;
  return (uint16_t)((c.u + 0x7FFFu + ((c.u >> 16) & 1u)) >> 16);
}
__device__ __forceinline__ void load8f(const void* p, size_t idx, int f32, float v[8]) {
  if (f32) {
    const float4* q = (const float4*)((const float*)p + idx);
    float4 a = q[0], b = q[1];
    v[0]=a.x; v[1]=a.y; v[2]=a.z; v[3]=a.w; v[4]=b.x; v[5]=b.y; v[6]=b.z; v[7]=b.w;
  } else {
    uint4 u = *(const uint4*)((const uint16_t*)p + idx);
    const uint32_t* w = (const uint32_t*)&u;
#pragma unroll
    for (int e = 0; e < 4; e++) { v[2*e] = bf2f(w[e] & 0xffffu); v[2*e+1] = bf2f(w[e] >> 16); }
  }
}
__device__ __forceinline__ float load1f(const void* p, size_t idx, int f32) {
  return f32 ? ((const float*)p)[idx] : bf2f(((const uint16_t*)p)[idx]);
}

// ---------------- pack (blocks 0..2047) + dtype detect (block 2048)
__global__ __launch_bounds__(256) void k_pd(const int* __restrict__ adj,
                                            unsigned long long* __restrict__ adjp,
                                            const uint16_t* __restrict__ x,
                                            int* __restrict__ flag) {
  if (blockIdx.x == 2048) {  // detect: bf16 N(0,1) never has exponent>=0x90
    __shared__ int s;
    if (threadIdx.x == 0) s = 0;
    __syncthreads();
    uint32_t bad = 0;
    for (int i = threadIdx.x; i < 4096; i += 256) {
      uint32_t ex = ((uint32_t)x[i] >> 7) & 0xffu;
      if (ex >= 0x90u) bad = 1;
    }
    if (__any(bad)) { if ((threadIdx.x & 63) == 0) atomicOr(&s, 1); }
    __syncthreads();
    if (threadIdx.x == 0) *flag = s;
    return;
  }
  const int row  = blockIdx.x * 4 + (threadIdx.x >> 6);
  const int lane = threadIdx.x & 63;
  const int* ar = adj + (size_t)row * N_;
#pragma unroll
  for (int c = 0; c < 16; c++) {
    unsigned long long m = __ballot(ar[c * 64 + lane] > 0);
    if (lane == 0) adjp[(size_t)row * 16 + c] = m;
  }
}

// ---------------- LN1 (blocks 0..2047) + W transpose (blocks 2048..2111)
__global__ __launch_bounds__(256) void k_prep(const void* __restrict__ x,
                                              const void* __restrict__ g,
                                              const void* __restrict__ bb,
                                              uint16_t* __restrict__ xn,
                                              const void* __restrict__ W,
                                              uint16_t* __restrict__ Wt,
                                              const int* __restrict__ flag) {
  const int f32 = *flag;
  if (blockIdx.x >= 2048) {  // W [H][D][DH] -> Wt [H][DH][D] bf16
    const int bx = blockIdx.x - 2048;
    const int h = bx >> 3, dt = bx & 7, t = threadIdx.x;
    __shared__ uint16_t tile[64][65];
    const size_t sbase = ((size_t)h * D_ + dt * 64) * DH_;
    for (int e = t; e < 4096; e += 256) tile[e >> 6][e & 63] = f2bf(load1f(W, sbase + e, f32));
    __syncthreads();
    uint16_t* dst = Wt + (size_t)h * DH_ * D_ + dt * 64;
    for (int e = t; e < 4096; e += 256) {
      const int k = e >> 6, dd = e & 63;
      dst[(size_t)k * D_ + dd] = tile[dd][k];
    }
    return;
  }
  const int row  = blockIdx.x * 4 + (threadIdx.x >> 6);
  const int lane = threadIdx.x & 63;
  const size_t base = (size_t)row * D_ + lane * 8;
  float v[8]; load8f(x, base, f32, v);
  float s = 0.f, sq = 0.f;
#pragma unroll
  for (int e = 0; e < 8; e++) { s += v[e]; sq += v[e] * v[e]; }
#pragma unroll
  for (int d = 32; d; d >>= 1) { s += __shfl_xor(s, d); sq += __shfl_xor(sq, d); }
  const float mean = s * (1.0f / D_);
  float var = fmaxf(sq * (1.0f / D_) - mean * mean, 0.0f);
  const float inv = 1.0f / (sqrtf(var) + 1e-6f);
  float gv[8], bv[8];
  load8f(g, lane * 8, f32, gv); load8f(bb, lane * 8, f32, bv);
  uint4 ov; uint32_t* ow = (uint32_t*)&ov;
#pragma unroll
  for (int e = 0; e < 4; e++) {
    float o0 = gv[2*e]   * ((v[2*e]   - mean) * inv) + bv[2*e];
    float o1 = gv[2*e+1] * ((v[2*e+1] - mean) * inv) + bv[2*e+1];
    ow[e] = (uint32_t)f2bf(o0) | ((uint32_t)f2bf(o1) << 16);
  }
  *(uint4*)(xn + base) = ov;
}

// ---------------- h = xn @ W per head -> ht[bh][dh][n] bf16, + fs/fd epilogue
__global__ __launch_bounds__(256, 4) void k_gemm(const uint16_t* __restrict__ xn,
                                              const uint16_t* __restrict__ Wt,
                                              uint16_t* __restrict__ ht,
                                              const void* __restrict__ asr,
                                              const void* __restrict__ adst,
                                              float* __restrict__ fs,
                                              float* __restrict__ fd,
                                              const int* __restrict__ flag) {
  const int h = blockIdx.x;
  const int r0 = blockIdx.y * 64;
  const int t = threadIdx.x;
  const int wv = t >> 6, lane = t & 63, q = lane >> 4, m16 = lane & 15;
  const int wr = wv >> 1, wc = wv & 1;

  __shared__ union {
    struct { __align__(16) uint16_t A[64 * 40]; __align__(16) uint16_t Bt[64 * 40]; } st;
    __align__(16) uint16_t tr[64 * 72];  // [dh][seq] transpose buffer
  } L;

  f32x4 acc[2][2] = {};
  const int srow = t >> 2, soff = (t & 3) * 8;
  const uint16_t* gA = xn + (size_t)(r0 + srow) * D_ + soff;
  const uint16_t* gB = Wt + ((size_t)h * DH_ + srow) * D_ + soff;
  uint16_t* lA = &L.st.A[srow * 40 + soff];
  uint16_t* lB = &L.st.Bt[srow * 40 + soff];

  for (int k0 = 0; k0 < D_; k0 += 32) {
    uint4 va = *(const uint4*)(gA + k0);
    uint4 vb = *(const uint4*)(gB + k0);
    __syncthreads();               // WAR
    *(uint4*)lA = va;
    *(uint4*)lB = vb;
    __syncthreads();               // RAW
    bf16x8 a0 = *(const bf16x8*)&L.st.A[(wr * 32 + m16) * 40 + q * 8];
    bf16x8 a1 = *(const bf16x8*)&L.st.A[(wr * 32 + 16 + m16) * 40 + q * 8];
    bf16x8 b0 = *(const bf16x8*)&L.st.Bt[(wc * 32 + m16) * 40 + q * 8];
    bf16x8 b1 = *(const bf16x8*)&L.st.Bt[(wc * 32 + 16 + m16) * 40 + q * 8];
    acc[0][0] = __builtin_amdgcn_mfma_f32_16x16x32_bf16(a0, b0, acc[0][0], 0, 0, 0);
    acc[0][1] = __builtin_amdgcn_mfma_f32_16x16x32_bf16(a0, b1, acc[0][1], 0, 0, 0);
    acc[1][0] = __builtin_amdgcn_mfma_f32_16x16x32_bf16(a1, b0, acc[1][0], 0, 0, 0);
    acc[1][1] = __builtin_amdgcn_mfma_f32_16x16x32_bf16(a1, b1, acc[1][1], 0, 0, 0);
  }
  __syncthreads();
#pragma unroll
  for (int i2 = 0; i2 < 2; i2++)
#pragma unroll
    for (int j2 = 0; j2 < 2; j2++) {
      f32x4 vv = acc[i2][j2];
      const int sl = wr * 32 + i2 * 16 + q * 4;   // seq-local
      const int kl = wc * 32 + j2 * 16 + m16;     // dh-local
#pragma unroll
      for (int r = 0; r < 4; r++) L.tr[kl * 72 + sl + r] = f2bf(vv[r]);
    }
  __syncthreads();
  const int b = r0 >> 10, n0 = r0 & 1023;
  {
    const int k = t >> 2, ns = (t & 3) * 16;
    const size_t base = (((size_t)b * H_ + h) * DH_ + k) * (size_t)N_ + n0 + ns;
    *(uint4*)(ht + base) = *(const uint4*)&L.tr[k * 72 + ns];
    *(uint4*)(ht + base + 8) = *(const uint4*)&L.tr[k * 72 + ns + 8];
  }
  {  // fused fs/fd: fs[bh][n] = sum_dh h[n][dh]*a_src[h][dh]
    const int f32 = *flag;
    const int nl = t >> 2, qd = (t & 3) * 16;
    float ss = 0.f, sd = 0.f;
#pragma unroll
    for (int dd = 0; dd < 16; dd++) {
      float hv = bf2f(L.tr[(qd + dd) * 72 + nl]);
      ss = fmaf(hv, load1f(asr,  h * DH_ + qd + dd, f32), ss);
      sd = fmaf(hv, load1f(adst, h * DH_ + qd + dd, f32), sd);
    }
    ss += __shfl_xor(ss, 1); ss += __shfl_xor(ss, 2);
    sd += __shfl_xor(sd, 1); sd += __shfl_xor(sd, 2);
    if ((t & 3) == 0) {
      fs[((size_t)b * H_ + h) * N_ + n0 + nl] = ss;
      fd[((size_t)b * H_ + h) * N_ + n0 + nl] = sd;
    }
  }
}

// ---------------- attention: out[i,dh] = (1/l_i) sum_j p_ij h[j,dh]
// p_ij = adj_ij * max(Es_i*Ed_j, Es2_i*Ed2_j); l_i from MFMA ones-rows tile.
__global__ __launch_bounds__(256, 3) void k_attn(const uint16_t* __restrict__ ht,
                                                 const float* __restrict__ fs,
                                                 const float* __restrict__ fd,
                                                 const uint32_t* __restrict__ adjp,
                                                 uint16_t* __restrict__ oat) {
  const int it = blockIdx.x, bh = blockIdx.y;
  const int b = bh >> 3, h = bh & 7;
  const int i0 = it * 64;
  const int t = threadIdx.x, wv = t >> 6, lane = t & 63, q = lane >> 4, m16 = lane & 15;
  __shared__ __align__(16) uint16_t Hs[80 * 264];  // rows 0..63: h-tile; 64..79: bf16 1.0
  __shared__ __align__(16) float2 Edi[N_];         // (e^{fd_j}, e^{0.2 fd_j})
  // prologue: per-j exp tables + ones rows
  for (int j = t; j < N_; j += 256) {
    float fdv = fd[(size_t)bh * N_ + j];
    Edi[j] = make_float2(exp2f(fdv * 1.44269504f), exp2f(fdv * 0.28853901f));
  }
  for (int e = t; e < 16 * 264; e += 256) Hs[64 * 264 + e] = 0x3F80u;  // 1.0bf16
  const int iA = i0 + wv * 16 + m16;
  const float fsv = fs[(size_t)bh * N_ + iA];
  const float Es  = exp2f(fsv * 1.44269504f);
  const float Es2 = exp2f(fsv * 0.28853901f);
  const uint4* arow4 = (const uint4*)(adjp + ((size_t)b * N_ + iA) * 32);
  const uint16_t* gH = ht + (size_t)bh * (DH_ * N_) + (size_t)(t >> 2) * N_ + (t & 3) * 8;
  uint16_t* lH = &Hs[(t >> 2) * 264 + (t & 3) * 8];
  f32x4 acc[5] = {};
  for (int c = 0; c < 4; c++) {
    const int jc = c * 256;
    uint4 aw0 = arow4[c * 2], aw1 = arow4[c * 2 + 1];
    uint4 hv[4];                   // two 4-uint4 staging batches: <=16 live regs
#pragma unroll
    for (int s = 0; s < 4; s++) hv[s] = *(const uint4*)(gH + jc + s * 32);
    __syncthreads();               // WAR (and prologue-RAW on c==0)
#pragma unroll
    for (int s = 0; s < 4; s++) *(uint4*)(lH + s * 32) = hv[s];
#pragma unroll
    for (int s = 0; s < 4; s++) hv[s] = *(const uint4*)(gH + jc + 128 + s * 32);
#pragma unroll
    for (int s = 0; s < 4; s++) *(uint4*)(lH + 128 + s * 32) = hv[s];
    __syncthreads();               // RAW
    const uint32_t aw[8] = {aw0.x, aw0.y, aw0.z, aw0.w, aw1.x, aw1.y, aw1.z, aw1.w};
#pragma unroll
    for (int s = 0; s < 8; s++) {
      const int jj = s * 32;
      const uint32_t abyte = (aw[s] >> (q * 8)) & 0xffu;
      const float2* ed = &Edi[jc + jj + q * 8];
      float4 e0 = *(const float4*)(ed);
      float4 e1 = *(const float4*)(ed + 2);
      float4 e2 = *(const float4*)(ed + 4);
      float4 e3 = *(const float4*)(ed + 6);
      float pm[8];
      pm[0] = fmaxf(Es * e0.x, Es2 * e0.y);
      pm[1] = fmaxf(Es * e0.z, Es2 * e0.w);
      pm[2] = fmaxf(Es * e1.x, Es2 * e1.y);
      pm[3] = fmaxf(Es * e1.z, Es2 * e1.w);
      pm[4] = fmaxf(Es * e2.x, Es2 * e2.y);
      pm[5] = fmaxf(Es * e2.z, Es2 * e2.w);
      pm[6] = fmaxf(Es * e3.x, Es2 * e3.y);
      pm[7] = fmaxf(Es * e3.z, Es2 * e3.w);
      union { __bf16 bv[8]; bf16x8 v; } af;
#pragma unroll
      for (int e = 0; e < 8; e++) {
        uint32_t msk = (uint32_t)(((int32_t)(abyte << (31 - e))) >> 31);  // sbfe
        af.bv[e] = (__bf16)__uint_as_float(__float_as_uint(pm[e]) & msk);
      }
#pragma unroll
      for (int nt = 0; nt < 5; nt++) {
        bf16x8 bfrag = *(const bf16x8*)&Hs[(nt * 16 + m16) * 264 + jj + q * 8];
        acc[nt] = __builtin_amdgcn_mfma_f32_16x16x32_bf16(af.v, bfrag, acc[nt], 0, 0, 0);
      }
    }
  }
  float linv[4];
#pragma unroll
  for (int r = 0; r < 4; r++) linv[r] = 1.0f / acc[4][r];  // l_i from ones-tile
  const int ibl = wv * 16 + q * 4;
#pragma unroll
  for (int nt = 0; nt < 4; nt++)
#pragma unroll
    for (int r = 0; r < 4; r++) {
      const int irow = i0 + ibl + r;
      oat[((size_t)b * N_ + irow) * D_ + h * DH_ + nt * 16 + m16] = f2bf(acc[nt][r] * linv[r]);
    }
}

// ---------------- final: y = LN2(x + elu(oat)); output dtype matches input
__global__ __launch_bounds__(256) void k_final(const void* __restrict__ x,
                                               const uint16_t* __restrict__ oa,
                                               const void* __restrict__ g,
                                               const void* __restrict__ bb,
                                               void* __restrict__ out,
                                               const int* __restrict__ flag) {
  const int f32 = *flag;
  const int row = blockIdx.x * 4 + (threadIdx.x >> 6);
  const int lane = threadIdx.x & 63;
  const size_t base = (size_t)row * D_ + lane * 8;
  float xv[8]; load8f(x, base, f32, xv);
  uint4 av = *(const uint4*)(oa + base);
  const uint32_t* aw = (const uint32_t*)&av;
  float v[8], s = 0.f, sq = 0.f;
#pragma unroll
  for (int e = 0; e < 4; e++) {
    float a0 = bf2f(aw[e] & 0xffffu), a1 = bf2f(aw[e] >> 16);
    a0 = a0 > 0.f ? a0 : exp2f(a0 * 1.44269504f) - 1.0f;
    a1 = a1 > 0.f ? a1 : exp2f(a1 * 1.44269504f) - 1.0f;
    float t0 = xv[2*e] + a0, t1 = xv[2*e+1] + a1;
    v[2*e] = t0; v[2*e+1] = t1;
    s += t0 + t1; sq += t0 * t0 + t1 * t1;
  }
#pragma unroll
  for (int d = 32; d; d >>= 1) { s += __shfl_xor(s, d); sq += __shfl_xor(sq, d); }
  const float mean = s * (1.0f / D_);
  float var = fmaxf(sq * (1.0f / D_) - mean * mean, 0.0f);
  const float inv = 1.0f / (sqrtf(var) + 1e-6f);
  float gv[8], bv[8];
  load8f(g, lane * 8, f32, gv); load8f(bb, lane * 8, f32, bv);
  float r8[8];
#pragma unroll
  for (int e = 0; e < 8; e++) r8[e] = gv[e] * ((v[e] - mean) * inv) + bv[e];
  if (f32) {
    float* o = (float*)out + base;
    float4 o0 = {r8[0], r8[1], r8[2], r8[3]};
    float4 o1 = {r8[4], r8[5], r8[6], r8[7]};
    *(float4*)(o) = o0;
    *(float4*)(o + 4) = o1;
  } else {
    uint4 ov; uint32_t* ow = (uint32_t*)&ov;
#pragma unroll
    for (int e = 0; e < 4; e++)
      ow[e] = (uint32_t)f2bf(r8[2*e]) | ((uint32_t)f2bf(r8[2*e+1]) << 16);
    *(uint4*)((uint16_t*)out + base) = ov;
  }
}

extern "C" void kernel_launch(void* const* d_in, const int* in_sizes, int n_in,
                              void* d_out, int out_size, void* d_ws, size_t ws_size,
                              hipStream_t stream) {
  const void* x = d_in[0];
  // d_in[1] = mask (unused)
  const int* adj = (const int*)d_in[2];
  const void* W = d_in[3];
  const void* asr = d_in[4];
  const void* adst = d_in[5];
  const void* g1 = d_in[6];
  const void* b1 = d_in[7];
  const void* g2 = d_in[8];
  const void* b2 = d_in[9];

  uint8_t* ws = (uint8_t*)d_ws;
  uint16_t* ht = (uint16_t*)(ws);                // 8 MB  [bh][dh][n] bf16
  uint16_t* xn = (uint16_t*)(ws + 8388608);      // 8 MB  (reused as oat)
  uint16_t* oat = xn;
  uint16_t* Wt = (uint16_t*)(ws + 16777216);     // 512 KB
  uint32_t* adjp = (uint32_t*)(ws + 17301504);   // 1 MB
  float* fs = (float*)(ws + 18350080);           // 256 KB
  float* fd = (float*)(ws + 18612224);           // 256 KB
  int* flag = (int*)(ws + 18874368);             // 4 B dtype flag

  k_pd<<<dim3(2049), dim3(256), 0, stream>>>(adj, (unsigned long long*)adjp,
                                             (const uint16_t*)x, flag);
  k_prep<<<dim3(2112), dim3(256), 0, stream>>>(x, g1, b1, xn, W, Wt, flag);
  k_gemm<<<dim3(8, 128), dim3(256), 0, stream>>>(xn, Wt, ht, asr, adst, fs, fd, flag);
  k_attn<<<dim3(16, 64), dim3(256), 0, stream>>>(ht, fs, fd, adjp, oat);
  k_final<<<dim3(2048), dim3(256), 0, stream>>>(x, oat, g2, b2, d_out, flag);
}

// Round 6
// 203.852 us; speedup vs baseline: 1.0358x; 1.0358x over previous
//
#include <hip/hip_runtime.h>
#include <stdint.h>

// Shapes (fixed by the reference)
#define B_ 8
#define N_ 1024
#define D_ 512
#define H_ 8
#define DH_ 64

// Round 6: barrier-free k_attn.
//  - R4/R5 lesson: registers live across in-loop barriers get spilled to
//    scratch (WRITE_SIZE 131/81 MB). Fix is structural: B-fragments are
//    16B-contiguous in ht[bh][dh][n] (contiguous in n=j), so load them
//    DIRECTLY from global -- no Hs LDS tile, no j-loop barriers at all.
//  - ones-tile denominator kept, but as a constant register fragment.
//  - k_pd + k_prep merged into k_pp (pack + detect + LN1 + Wt); LN1/Wt
//    blocks do inline dtype detection (no intra-kernel flag dependency).

using bf16x8 = __attribute__((ext_vector_type(8))) __bf16;
using f32x4  = __attribute__((ext_vector_type(4))) float;

__device__ __forceinline__ float bf2f(uint32_t u) {
  union { uint32_t u; float f; } c; c.u = u << 16; return c.f;
}
__device__ __forceinline__ uint16_t f2bf(float f) {  // RNE
  union { float f; uint32_t u; } c; c.f = f;
  return (uint16_t)((c.u + 0x7FFFu + ((c.u >> 16) & 1u)) >> 16);
}
__device__ __forceinline__ void load8f(const void* p, size_t idx, int f32, float v[8]) {
  if (f32) {
    const float4* q = (const float4*)((const float*)p + idx);
    float4 a = q[0], b = q[1];
    v[0]=a.x; v[1]=a.y; v[2]=a.z; v[3]=a.w; v[4]=b.x; v[5]=b.y; v[6]=b.z; v[7]=b.w;
  } else {
    uint4 u = *(const uint4*)((const uint16_t*)p + idx);
    const uint32_t* w = (const uint32_t*)&u;
#pragma unroll
    for (int e = 0; e < 4; e++) { v[2*e] = bf2f(w[e] & 0xffffu); v[2*e+1] = bf2f(w[e] >> 16); }
  }
}
__device__ __forceinline__ float load1f(const void* p, size_t idx, int f32) {
  return f32 ? ((const float*)p)[idx] : bf2f(((const uint16_t*)p)[idx]);
}

// block-local dtype detect: scan first 1024 uint16 of x; bf16 N(0,1) never
// has bf16-exponent >= 0x90 (|v|>=2^17); fp32-as-u16 halves are ~uniform.
__device__ __forceinline__ int detect_f32_block(const uint16_t* x, int t, int* sflag) {
  if (t == 0) *sflag = 0;
  __syncthreads();
  uint2 u = ((const uint2*)x)[t];
  uint32_t bad = 0;
  bad |= (((u.x >> 7)  & 0xffu) >= 0x90u);
  bad |= (((u.x >> 23) & 0xffu) >= 0x90u);
  bad |= (((u.y >> 7)  & 0xffu) >= 0x90u);
  bad |= (((u.y >> 23) & 0xffu) >= 0x90u);
  if (__any(bad)) { if ((t & 63) == 0) atomicOr(sflag, 1); }
  __syncthreads();
  return *sflag;
}

// ---------------- k_pp: adj pack (0..2047) | detect->flag (2048) |
//                  LN1 (2049..4096) | W transpose (4097..4160)
__global__ __launch_bounds__(256) void k_pp(const int* __restrict__ adj,
                                            unsigned long long* __restrict__ adjp,
                                            const uint16_t* __restrict__ xr,
                                            int* __restrict__ flag,
                                            const void* __restrict__ x,
                                            const void* __restrict__ g,
                                            const void* __restrict__ bb,
                                            uint16_t* __restrict__ xn,
                                            const void* __restrict__ W,
                                            uint16_t* __restrict__ Wt) {
  const int bx = blockIdx.x, t = threadIdx.x;
  if (bx < 2048) {  // adjacency bit-pack
    const int row  = bx * 4 + (t >> 6);
    const int lane = t & 63;
    const int* ar = adj + (size_t)row * N_;
#pragma unroll
    for (int c = 0; c < 16; c++) {
      unsigned long long m = __ballot(ar[c * 64 + lane] > 0);
      if (lane == 0) adjp[(size_t)row * 16 + c] = m;
    }
    return;
  }
  __shared__ int sflag;
  if (bx == 2048) {  // global flag for k_gemm / k_final
    int f32 = detect_f32_block(xr, t, &sflag);
    if (t == 0) *flag = f32;
    return;
  }
  if (bx >= 4097) {  // W [H][D][DH] -> Wt [H][DH][D] bf16
    const int f32 = detect_f32_block(xr, t, &sflag);
    const int bw = bx - 4097;
    const int h = bw >> 3, dt = bw & 7;
    __shared__ uint16_t tile[64][65];
    const size_t sbase = ((size_t)h * D_ + dt * 64) * DH_;
    for (int e = t; e < 4096; e += 256) tile[e >> 6][e & 63] = f2bf(load1f(W, sbase + e, f32));
    __syncthreads();
    uint16_t* dst = Wt + (size_t)h * DH_ * D_ + dt * 64;
    for (int e = t; e < 4096; e += 256) {
      const int k = e >> 6, dd = e & 63;
      dst[(size_t)k * D_ + dd] = tile[dd][k];
    }
    return;
  }
  // LayerNorm1
  const int f32 = detect_f32_block(xr, t, &sflag);
  const int row  = (bx - 2049) * 4 + (t >> 6);
  const int lane = t & 63;
  const size_t base = (size_t)row * D_ + lane * 8;
  float v[8]; load8f(x, base, f32, v);
  float s = 0.f, sq = 0.f;
#pragma unroll
  for (int e = 0; e < 8; e++) { s += v[e]; sq += v[e] * v[e]; }
#pragma unroll
  for (int d = 32; d; d >>= 1) { s += __shfl_xor(s, d); sq += __shfl_xor(sq, d); }
  const float mean = s * (1.0f / D_);
  float var = fmaxf(sq * (1.0f / D_) - mean * mean, 0.0f);
  const float inv = 1.0f / (sqrtf(var) + 1e-6f);
  float gv[8], bv[8];
  load8f(g, lane * 8, f32, gv); load8f(bb, lane * 8, f32, bv);
  uint4 ov; uint32_t* ow = (uint32_t*)&ov;
#pragma unroll
  for (int e = 0; e < 4; e++) {
    float o0 = gv[2*e]   * ((v[2*e]   - mean) * inv) + bv[2*e];
    float o1 = gv[2*e+1] * ((v[2*e+1] - mean) * inv) + bv[2*e+1];
    ow[e] = (uint32_t)f2bf(o0) | ((uint32_t)f2bf(o1) << 16);
  }
  *(uint4*)(xn + base) = ov;
}

// ---------------- h = xn @ W per head -> ht[bh][dh][n] bf16, + fs/fd epilogue
__global__ __launch_bounds__(256, 4) void k_gemm(const uint16_t* __restrict__ xn,
                                              const uint16_t* __restrict__ Wt,
                                              uint16_t* __restrict__ ht,
                                              const void* __restrict__ asr,
                                              const void* __restrict__ adst,
                                              float* __restrict__ fs,
                                              float* __restrict__ fd,
                                              const int* __restrict__ flag) {
  const int h = blockIdx.x;
  const int r0 = blockIdx.y * 64;
  const int t = threadIdx.x;
  const int wv = t >> 6, lane = t & 63, q = lane >> 4, m16 = lane & 15;
  const int wr = wv >> 1, wc = wv & 1;

  __shared__ union {
    struct { __align__(16) uint16_t A[64 * 40]; __align__(16) uint16_t Bt[64 * 40]; } st;
    __align__(16) uint16_t tr[64 * 72];  // [dh][seq] transpose buffer
  } L;

  f32x4 acc[2][2] = {};
  const int srow = t >> 2, soff = (t & 3) * 8;
  const uint16_t* gA = xn + (size_t)(r0 + srow) * D_ + soff;
  const uint16_t* gB = Wt + ((size_t)h * DH_ + srow) * D_ + soff;
  uint16_t* lA = &L.st.A[srow * 40 + soff];
  uint16_t* lB = &L.st.Bt[srow * 40 + soff];

  for (int k0 = 0; k0 < D_; k0 += 32) {
    uint4 va = *(const uint4*)(gA + k0);
    uint4 vb = *(const uint4*)(gB + k0);
    __syncthreads();               // WAR
    *(uint4*)lA = va;
    *(uint4*)lB = vb;
    __syncthreads();               // RAW
    bf16x8 a0 = *(const bf16x8*)&L.st.A[(wr * 32 + m16) * 40 + q * 8];
    bf16x8 a1 = *(const bf16x8*)&L.st.A[(wr * 32 + 16 + m16) * 40 + q * 8];
    bf16x8 b0 = *(const bf16x8*)&L.st.Bt[(wc * 32 + m16) * 40 + q * 8];
    bf16x8 b1 = *(const bf16x8*)&L.st.Bt[(wc * 32 + 16 + m16) * 40 + q * 8];
    acc[0][0] = __builtin_amdgcn_mfma_f32_16x16x32_bf16(a0, b0, acc[0][0], 0, 0, 0);
    acc[0][1] = __builtin_amdgcn_mfma_f32_16x16x32_bf16(a0, b1, acc[0][1], 0, 0, 0);
    acc[1][0] = __builtin_amdgcn_mfma_f32_16x16x32_bf16(a1, b0, acc[1][0], 0, 0, 0);
    acc[1][1] = __builtin_amdgcn_mfma_f32_16x16x32_bf16(a1, b1, acc[1][1], 0, 0, 0);
  }
  __syncthreads();
#pragma unroll
  for (int i2 = 0; i2 < 2; i2++)
#pragma unroll
    for (int j2 = 0; j2 < 2; j2++) {
      f32x4 vv = acc[i2][j2];
      const int sl = wr * 32 + i2 * 16 + q * 4;   // seq-local
      const int kl = wc * 32 + j2 * 16 + m16;     // dh-local
#pragma unroll
      for (int r = 0; r < 4; r++) L.tr[kl * 72 + sl + r] = f2bf(vv[r]);
    }
  __syncthreads();
  const int b = r0 >> 10, n0 = r0 & 1023;
  {
    const int k = t >> 2, ns = (t & 3) * 16;
    const size_t base = (((size_t)b * H_ + h) * DH_ + k) * (size_t)N_ + n0 + ns;
    *(uint4*)(ht + base) = *(const uint4*)&L.tr[k * 72 + ns];
    *(uint4*)(ht + base + 8) = *(const uint4*)&L.tr[k * 72 + ns + 8];
  }
  {  // fused fs/fd: fs[bh][n] = sum_dh h[n][dh]*a_src[h][dh]
    const int f32 = *flag;
    const int nl = t >> 2, qd = (t & 3) * 16;
    float ss = 0.f, sd = 0.f;
#pragma unroll
    for (int dd = 0; dd < 16; dd++) {
      float hv = bf2f(L.tr[(qd + dd) * 72 + nl]);
      ss = fmaf(hv, load1f(asr,  h * DH_ + qd + dd, f32), ss);
      sd = fmaf(hv, load1f(adst, h * DH_ + qd + dd, f32), sd);
    }
    ss += __shfl_xor(ss, 1); ss += __shfl_xor(ss, 2);
    sd += __shfl_xor(sd, 1); sd += __shfl_xor(sd, 2);
    if ((t & 3) == 0) {
      fs[((size_t)b * H_ + h) * N_ + n0 + nl] = ss;
      fd[((size_t)b * H_ + h) * N_ + n0 + nl] = sd;
    }
  }
}

// ---------------- attention: out[i,dh] = (1/l_i) sum_j p_ij h[j,dh]
// p_ij = adj_ij * max(Es_i*Ed_j, Es2_i*Ed2_j); B-frags loaded DIRECTLY from
// global ht (contiguous in j) -- no LDS tile, no j-loop barriers.
__global__ __launch_bounds__(256, 2) void k_attn(const uint16_t* __restrict__ ht,
                                                 const float* __restrict__ fs,
                                                 const float* __restrict__ fd,
                                                 const uint32_t* __restrict__ adjp,
                                                 uint16_t* __restrict__ oat) {
  const int it = blockIdx.x, bh = blockIdx.y;
  const int b = bh >> 3, h = bh & 7;
  const int i0 = it * 64;
  const int t = threadIdx.x, wv = t >> 6, lane = t & 63, q = lane >> 4, m16 = lane & 15;
  __shared__ __align__(16) float2 Edi[N_];  // (e^{fd_j}, e^{0.2 fd_j})
  for (int j = t; j < N_; j += 256) {
    float fdv = fd[(size_t)bh * N_ + j];
    Edi[j] = make_float2(exp2f(fdv * 1.44269504f), exp2f(fdv * 0.28853901f));
  }
  const int iA = i0 + wv * 16 + m16;
  const float fsv = fs[(size_t)bh * N_ + iA];
  const float Es  = exp2f(fsv * 1.44269504f);
  const float Es2 = exp2f(fsv * 0.28853901f);
  const uint4* arow4 = (const uint4*)(adjp + ((size_t)b * N_ + iA) * 32);
  const uint16_t* gB = ht + (size_t)bh * (DH_ * N_) + (size_t)m16 * N_ + q * 8;
  union { uint16_t u[8]; bf16x8 v; } ones;
#pragma unroll
  for (int e = 0; e < 8; e++) ones.u[e] = 0x3F80u;  // 1.0 bf16
  f32x4 acc[5] = {};
  __syncthreads();  // Edi ready (only barrier)
  for (int c = 0; c < 4; c++) {
    uint4 aw0 = arow4[c * 2], aw1 = arow4[c * 2 + 1];
    const uint32_t aw[8] = {aw0.x, aw0.y, aw0.z, aw0.w, aw1.x, aw1.y, aw1.z, aw1.w};
#pragma unroll
    for (int s = 0; s < 8; s++) {
      const int j0 = c * 256 + s * 32;
      bf16x8 bf0 = *(const bf16x8*)(gB + j0);            // dh = m16
      bf16x8 bf1 = *(const bf16x8*)(gB + 16 * N_ + j0);  // dh = 16+m16
      bf16x8 bf2 = *(const bf16x8*)(gB + 32 * N_ + j0);  // dh = 32+m16
      bf16x8 bf3 = *(const bf16x8*)(gB + 48 * N_ + j0);  // dh = 48+m16
      const uint32_t abyte = (aw[s] >> (q * 8)) & 0xffu;
      const float2* ed = &Edi[j0 + q * 8];
      float4 e0 = *(const float4*)(ed);
      float4 e1 = *(const float4*)(ed + 2);
      float4 e2 = *(const float4*)(ed + 4);
      float4 e3 = *(const float4*)(ed + 6);
      float pm[8];
      pm[0] = fmaxf(Es * e0.x, Es2 * e0.y);
      pm[1] = fmaxf(Es * e0.z, Es2 * e0.w);
      pm[2] = fmaxf(Es * e1.x, Es2 * e1.y);
      pm[3] = fmaxf(Es * e1.z, Es2 * e1.w);
      pm[4] = fmaxf(Es * e2.x, Es2 * e2.y);
      pm[5] = fmaxf(Es * e2.z, Es2 * e2.w);
      pm[6] = fmaxf(Es * e3.x, Es2 * e3.y);
      pm[7] = fmaxf(Es * e3.z, Es2 * e3.w);
      union { __bf16 bv[8]; bf16x8 v; } af;
#pragma unroll
      for (int e = 0; e < 8; e++) {
        uint32_t msk = (uint32_t)(((int32_t)(abyte << (31 - e))) >> 31);
        af.bv[e] = (__bf16)__uint_as_float(__float_as_uint(pm[e]) & msk);
      }
      acc[0] = __builtin_amdgcn_mfma_f32_16x16x32_bf16(af.v, bf0, acc[0], 0, 0, 0);
      acc[1] = __builtin_amdgcn_mfma_f32_16x16x32_bf16(af.v, bf1, acc[1], 0, 0, 0);
      acc[2] = __builtin_amdgcn_mfma_f32_16x16x32_bf16(af.v, bf2, acc[2], 0, 0, 0);
      acc[3] = __builtin_amdgcn_mfma_f32_16x16x32_bf16(af.v, bf3, acc[3], 0, 0, 0);
      acc[4] = __builtin_amdgcn_mfma_f32_16x16x32_bf16(af.v, ones.v, acc[4], 0, 0, 0);
    }
  }
  float linv[4];
#pragma unroll
  for (int r = 0; r < 4; r++) linv[r] = 1.0f / acc[4][r];  // l_i from ones-tile
  const int ibl = wv * 16 + q * 4;
#pragma unroll
  for (int nt = 0; nt < 4; nt++)
#pragma unroll
    for (int r = 0; r < 4; r++) {
      const int irow = i0 + ibl + r;
      oat[((size_t)b * N_ + irow) * D_ + h * DH_ + nt * 16 + m16] = f2bf(acc[nt][r] * linv[r]);
    }
}

// ---------------- final: y = LN2(x + elu(oat)); output dtype matches input
__global__ __launch_bounds__(256) void k_final(const void* __restrict__ x,
                                               const uint16_t* __restrict__ oa,
                                               const void* __restrict__ g,
                                               const void* __restrict__ bb,
                                               void* __restrict__ out,
                                               const int* __restrict__ flag) {
  const int f32 = *flag;
  const int row = blockIdx.x * 4 + (threadIdx.x >> 6);
  const int lane = threadIdx.x & 63;
  const size_t base = (size_t)row * D_ + lane * 8;
  float xv[8]; load8f(x, base, f32, xv);
  uint4 av = *(const uint4*)(oa + base);
  const uint32_t* aw = (const uint32_t*)&av;
  float v[8], s = 0.f, sq = 0.f;
#pragma unroll
  for (int e = 0; e < 4; e++) {
    float a0 = bf2f(aw[e] & 0xffffu), a1 = bf2f(aw[e] >> 16);
    a0 = a0 > 0.f ? a0 : exp2f(a0 * 1.44269504f) - 1.0f;
    a1 = a1 > 0.f ? a1 : exp2f(a1 * 1.44269504f) - 1.0f;
    float t0 = xv[2*e] + a0, t1 = xv[2*e+1] + a1;
    v[2*e] = t0; v[2*e+1] = t1;
    s += t0 + t1; sq += t0 * t0 + t1 * t1;
  }
#pragma unroll
  for (int d = 32; d; d >>= 1) { s += __shfl_xor(s, d); sq += __shfl_xor(sq, d); }
  const float mean = s * (1.0f / D_);
  float var = fmaxf(sq * (1.0f / D_) - mean * mean, 0.0f);
  const float inv = 1.0f / (sqrtf(var) + 1e-6f);
  float gv[8], bv[8];
  load8f(g, lane * 8, f32, gv); load8f(bb, lane * 8, f32, bv);
  float r8[8];
#pragma unroll
  for (int e = 0; e < 8; e++) r8[e] = gv[e] * ((v[e] - mean) * inv) + bv[e];
  if (f32) {
    float* o = (float*)out + base;
    float4 o0 = {r8[0], r8[1], r8[2], r8[3]};
    float4 o1 = {r8[4], r8[5], r8[6], r8[7]};
    *(float4*)(o) = o0;
    *(float4*)(o + 4) = o1;
  } else {
    uint4 ov; uint32_t* ow = (uint32_t*)&ov;
#pragma unroll
    for (int e = 0; e < 4; e++)
      ow[e] = (uint32_t)f2bf(r8[2*e]) | ((uint32_t)f2bf(r8[2*e+1]) << 16);
    *(uint4*)((uint16_t*)out + base) = ov;
  }
}

extern "C" void kernel_launch(void* const* d_in, const int* in_sizes, int n_in,
                              void* d_out, int out_size, void* d_ws, size_t ws_size,
                              hipStream_t stream) {
  const void* x = d_in[0];
  // d_in[1] = mask (unused)
  const int* adj = (const int*)d_in[2];
  const void* W = d_in[3];
  const void* asr = d_in[4];
  const void* adst = d_in[5];
  const void* g1 = d_in[6];
  const void* b1 = d_in[7];
  const void* g2 = d_in[8];
  const void* b2 = d_in[9];

  uint8_t* ws = (uint8_t*)d_ws;
  uint16_t* ht = (uint16_t*)(ws);                // 8 MB  [bh][dh][n] bf16
  uint16_t* xn = (uint16_t*)(ws + 8388608);      // 8 MB  (reused as oat)
  uint16_t* oat = xn;
  uint16_t* Wt = (uint16_t*)(ws + 16777216);     // 512 KB
  uint32_t* adjp = (uint32_t*)(ws + 17301504);   // 1 MB
  float* fs = (float*)(ws + 18350080);           // 256 KB
  float* fd = (float*)(ws + 18612224);           // 256 KB
  int* flag = (int*)(ws + 18874368);             // 4 B dtype flag

  k_pp<<<dim3(4161), dim3(256), 0, stream>>>(adj, (unsigned long long*)adjp,
                                             (const uint16_t*)x, flag,
                                             x, g1, b1, xn, W, Wt);
  k_gemm<<<dim3(8, 128), dim3(256), 0, stream>>>(xn, Wt, ht, asr, adst, fs, fd, flag);
  k_attn<<<dim3(16, 64), dim3(256), 0, stream>>>(ht, fs, fd, adjp, oat);
  k_final<<<dim3(2048), dim3(256), 0, stream>>>(x, oat, g2, b2, d_out, flag);
}